// Round 4
// baseline (1697.725 us; speedup 1.0000x reference)
//
#include <hip/hip_runtime.h>
#include <hip/hip_bf16.h>

// Problem constants (B=1, S=2048, H=1024, E=8, K=2, F=4096)
#define T_ 2048
#define H_ 1024
#define E_ 8
#define F_ 4096

#define BM 128
#define BN 128
#define BK 32

typedef __attribute__((ext_vector_type(8))) short short8;
typedef __attribute__((ext_vector_type(4))) float f32x4;

__device__ __forceinline__ unsigned short f2bf(float f) {
    union { float f; unsigned u; } a; a.f = f;
    unsigned r = a.u + 0x7fffu + ((a.u >> 16) & 1u);   // RNE (finite inputs)
    return (unsigned short)(r >> 16);
}

__device__ __forceinline__ short8 pack8(float4 a, float4 b) {
    short8 r;
    r[0] = (short)f2bf(a.x); r[1] = (short)f2bf(a.y);
    r[2] = (short)f2bf(a.z); r[3] = (short)f2bf(a.w);
    r[4] = (short)f2bf(b.x); r[5] = (short)f2bf(b.y);
    r[6] = (short)f2bf(b.z); r[7] = (short)f2bf(b.w);
    return r;
}

__device__ __forceinline__ void gld_lds16(const void* g, void* l) {
    __builtin_amdgcn_global_load_lds(
        (const __attribute__((address_space(1))) unsigned int*)g,
        (__attribute__((address_space(3))) unsigned int*)l,
        16, 0, 0);
}

// ---------------- Kernel 1: LayerNorm + residual copy + gating ----------------
__global__ __launch_bounds__(256) void ln_gate_kernel(
    const float* __restrict__ x, const float* __restrict__ lnw,
    const float* __restrict__ lnb, const float* __restrict__ gatew,
    float* __restrict__ out, unsigned short* __restrict__ xn,
    int* __restrict__ tok, float* __restrict__ gwslot, int* __restrict__ cnt)
{
    int t = blockIdx.x;
    int tid = threadIdx.x;
    const float4* xr = reinterpret_cast<const float4*>(x + (size_t)t * H_);
    float4 v = xr[tid];
    float s  = v.x + v.y + v.z + v.w;
    float ss = v.x*v.x + v.y*v.y + v.z*v.z + v.w*v.w;
    #pragma unroll
    for (int off = 32; off >= 1; off >>= 1) {
        s  += __shfl_xor(s, off);
        ss += __shfl_xor(ss, off);
    }
    __shared__ float redS[4], redQ[4];
    __shared__ float gred[4][E_];
    int wv = tid >> 6;
    if ((tid & 63) == 0) { redS[wv] = s; redQ[wv] = ss; }
    __syncthreads();
    s  = redS[0] + redS[1] + redS[2] + redS[3];
    ss = redQ[0] + redQ[1] + redQ[2] + redQ[3];
    float mu  = s * (1.0f / H_);
    float var = ss * (1.0f / H_) - mu * mu;
    float inv = rsqrtf(var + 1e-5f);

    float4 w4 = reinterpret_cast<const float4*>(lnw)[tid];
    float4 b4 = reinterpret_cast<const float4*>(lnb)[tid];
    float n0 = (v.x - mu) * inv * w4.x + b4.x;
    float n1 = (v.y - mu) * inv * w4.y + b4.y;
    float n2 = (v.z - mu) * inv * w4.z + b4.z;
    float n3 = (v.w - mu) * inv * w4.w + b4.w;

    // store normed activation as bf16
    ushort4 pk = make_ushort4(f2bf(n0), f2bf(n1), f2bf(n2), f2bf(n3));
    reinterpret_cast<ushort4*>(xn + (size_t)t * H_)[tid] = pk;
    // residual init: out = x
    reinterpret_cast<float4*>(out + (size_t)t * H_)[tid] = v;

    // gating logits in fp32
    float lg[E_];
    #pragma unroll
    for (int e = 0; e < E_; ++e) {
        float4 g4 = reinterpret_cast<const float4*>(gatew + (size_t)e * H_)[tid];
        lg[e] = n0*g4.x + n1*g4.y + n2*g4.z + n3*g4.w;
    }
    #pragma unroll
    for (int e = 0; e < E_; ++e) {
        #pragma unroll
        for (int off = 32; off >= 1; off >>= 1)
            lg[e] += __shfl_xor(lg[e], off);
    }
    if ((tid & 63) == 0) {
        #pragma unroll
        for (int e = 0; e < E_; ++e) gred[wv][e] = lg[e];
    }
    __syncthreads();
    if (tid == 0) {
        float logit[E_]; float mx = -1e30f;
        #pragma unroll
        for (int e = 0; e < E_; ++e) {
            logit[e] = gred[0][e] + gred[1][e] + gred[2][e] + gred[3][e];
            mx = fmaxf(mx, logit[e]);
        }
        float p[E_]; float sum = 0.f;
        #pragma unroll
        for (int e = 0; e < E_; ++e) { p[e] = expf(logit[e] - mx); sum += p[e]; }
        int i0 = 0;
        #pragma unroll
        for (int e = 1; e < E_; ++e) if (logit[e] > logit[i0]) i0 = e;
        int i1 = (i0 == 0) ? 1 : 0;
        #pragma unroll
        for (int e = 0; e < E_; ++e) if (e != i0 && logit[e] > logit[i1]) i1 = e;
        float p0 = p[i0] / sum, p1 = p[i1] / sum;
        float dn = p0 + p1 + 1e-8f;
        float w0 = p0 / dn, w1 = p1 / dn;
        int pos0 = atomicAdd(&cnt[i0], 1);
        tok[i0 * T_ + pos0] = t; gwslot[i0 * T_ + pos0] = w0;
        int pos1 = atomicAdd(&cnt[i1], 1);
        tok[i1 * T_ + pos1] = t; gwslot[i1 * T_ + pos1] = w1;
    }
}

// ---------------- Kernel 2: lbl scalar + prefix offsets ----------------
__global__ void finalize_kernel(const int* __restrict__ cnt, int* __restrict__ offs,
                                float* __restrict__ lbl_out)
{
    if (threadIdx.x == 0 && blockIdx.x == 0) {
        int c[E_]; int tot = 0;
        #pragma unroll
        for (int e = 0; e < E_; ++e) { c[e] = cnt[e]; tot += c[e]; }
        int o = 0;
        #pragma unroll
        for (int e = 0; e < E_; ++e) { offs[e] = o; o += c[e]; }
        float itot = 1.0f / (float)tot;
        float u[E_]; float mean = 0.f;
        #pragma unroll
        for (int e = 0; e < E_; ++e) { u[e] = c[e] * itot; mean += u[e]; }
        mean *= (1.0f / E_);
        float var = 0.f;
        #pragma unroll
        for (int e = 0; e < E_; ++e) { float d = u[e] - mean; var += d * d; }
        var *= (1.0f / (E_ - 1));
        float l = var / (mean + 1e-8f);
        lbl_out[0] = l * l;
    }
}

// ---------------- Kernel 3: grouped g/u GEMM + silu -> h (bf16) ----------------
__global__ __launch_bounds__(256) void gu_kernel(
    const float* __restrict__ Wg, const float* __restrict__ Wu,
    const unsigned short* __restrict__ xn,
    const int* __restrict__ tok, const int* __restrict__ cnt,
    const int* __restrict__ offs, unsigned short* __restrict__ hbuf)
{
    int ti = blockIdx.x, fj = blockIdx.y, e = blockIdx.z;
    int Te = cnt[e];
    int base = ti * BM;
    if (base >= Te) return;
    int rows = Te - base; if (rows > BM) rows = BM;

    __shared__ unsigned short As[BM][BK];
    __shared__ unsigned short Bgs[BN][BK];
    __shared__ unsigned short Bus[BN][BK];
    __shared__ int toks[BM];

    int tid = threadIdx.x;
    if (tid < BM) {
        int r = base + tid;
        toks[tid] = tok[e * T_ + (r < Te ? r : Te - 1)];
    }
    __syncthreads();

    int w = tid >> 6, l = tid & 63;
    int lr = l & 15, kb8 = (l >> 4) * 8;
    int arow0 = tid >> 2, achk = tid & 3;
    const unsigned short* ag0 = xn + (size_t)toks[arow0]      * H_ + achk * 8;
    const unsigned short* ag1 = xn + (size_t)toks[arow0 + 64] * H_ + achk * 8;

    int brow = tid >> 1, bhalf = tid & 1;
    const float* wgp = Wg + ((size_t)e * F_ + (size_t)fj * BN + brow) * H_ + bhalf * 16;
    const float* wup = Wu + ((size_t)e * F_ + (size_t)fj * BN + brow) * H_ + bhalf * 16;

    f32x4 zero4 = {0.f, 0.f, 0.f, 0.f};
    f32x4 accg[4][4], accu[4][4];
    #pragma unroll
    for (int m = 0; m < 4; ++m)
        #pragma unroll
        for (int n = 0; n < 4; ++n) { accg[m][n] = zero4; accu[m][n] = zero4; }

    for (int it = 0; it < H_ / BK; ++it) {
        int k0 = it * BK;
        __syncthreads();
        // stage A (bf16, gathered rows) via async global->LDS
        gld_lds16(ag0 + k0, (char*)&As[0][0] + w * 1024);
        gld_lds16(ag1 + k0, (char*)&As[0][0] + 4096 + w * 1024);
        // stage B tiles (fp32 -> bf16 via regs)
        float4 g0 = *(const float4*)(wgp + k0);
        float4 g1 = *(const float4*)(wgp + k0 + 4);
        float4 g2 = *(const float4*)(wgp + k0 + 8);
        float4 g3 = *(const float4*)(wgp + k0 + 12);
        float4 u0 = *(const float4*)(wup + k0);
        float4 u1 = *(const float4*)(wup + k0 + 4);
        float4 u2 = *(const float4*)(wup + k0 + 8);
        float4 u3 = *(const float4*)(wup + k0 + 12);
        *(short8*)(&Bgs[brow][bhalf * 16])     = pack8(g0, g1);
        *(short8*)(&Bgs[brow][bhalf * 16 + 8]) = pack8(g2, g3);
        *(short8*)(&Bus[brow][bhalf * 16])     = pack8(u0, u1);
        *(short8*)(&Bus[brow][bhalf * 16 + 8]) = pack8(u2, u3);
        __syncthreads();

        int wr = w >> 1, wc = w & 1;
        short8 af[4];
        #pragma unroll
        for (int m = 0; m < 4; ++m)
            af[m] = *(const short8*)&As[wr * 64 + m * 16 + lr][kb8];
        #pragma unroll
        for (int n = 0; n < 4; ++n) {
            short8 bgn = *(const short8*)&Bgs[wc * 64 + n * 16 + lr][kb8];
            #pragma unroll
            for (int m = 0; m < 4; ++m)
                accg[m][n] = __builtin_amdgcn_mfma_f32_16x16x32_bf16(af[m], bgn, accg[m][n], 0, 0, 0);
        }
        #pragma unroll
        for (int n = 0; n < 4; ++n) {
            short8 bun = *(const short8*)&Bus[wc * 64 + n * 16 + lr][kb8];
            #pragma unroll
            for (int m = 0; m < 4; ++m)
                accu[m][n] = __builtin_amdgcn_mfma_f32_16x16x32_bf16(af[m], bun, accu[m][n], 0, 0, 0);
        }
    }

    // epilogue: h = g * silu(u), bf16
    int wr = w >> 1, wc = w & 1;
    size_t slotbase = (size_t)offs[e] + base;
    #pragma unroll
    for (int m = 0; m < 4; ++m) {
        #pragma unroll
        for (int n = 0; n < 4; ++n) {
            int col = fj * BN + wc * 64 + n * 16 + lr;
            #pragma unroll
            for (int q = 0; q < 4; ++q) {
                int row = wr * 64 + m * 16 + (l >> 4) * 4 + q;
                if (row < rows) {
                    float uu = accu[m][n][q];
                    float hh = accg[m][n][q] * (uu / (1.f + expf(-uu)));
                    hbuf[(slotbase + row) * F_ + col] = f2bf(hh);
                }
            }
        }
    }
}

// ---------------- Kernel 4: grouped down GEMM + gated scatter ----------------
__global__ __launch_bounds__(256) void down_kernel(
    const float* __restrict__ Wd, const unsigned short* __restrict__ hbuf,
    const int* __restrict__ tok, const int* __restrict__ cnt,
    const int* __restrict__ offs, const float* __restrict__ gwslot,
    float* __restrict__ out)
{
    int ti = blockIdx.x, hj = blockIdx.y, e = blockIdx.z;
    int Te = cnt[e];
    int base = ti * BM;
    if (base >= Te) return;
    int rows = Te - base; if (rows > BM) rows = BM;

    __shared__ unsigned short As[BM][BK];
    __shared__ unsigned short Bs[BN][BK];

    int tid = threadIdx.x;
    int w = tid >> 6, l = tid & 63;
    int lr = l & 15, kb8 = (l >> 4) * 8;
    int arow0 = tid >> 2, achk = tid & 3;
    size_t slot0 = (size_t)offs[e] + base;
    size_t ar0 = slot0 + arow0;      if (ar0 > (size_t)(T_ * 2 - 1)) ar0 = T_ * 2 - 1;
    size_t ar1 = slot0 + arow0 + 64; if (ar1 > (size_t)(T_ * 2 - 1)) ar1 = T_ * 2 - 1;
    const unsigned short* ag0 = hbuf + ar0 * F_ + achk * 8;
    const unsigned short* ag1 = hbuf + ar1 * F_ + achk * 8;

    int brow = tid >> 1, bhalf = tid & 1;
    const float* wdp = Wd + ((size_t)e * H_ + (size_t)hj * BN + brow) * F_ + bhalf * 16;

    f32x4 zero4 = {0.f, 0.f, 0.f, 0.f};
    f32x4 acc[4][4];
    #pragma unroll
    for (int m = 0; m < 4; ++m)
        #pragma unroll
        for (int n = 0; n < 4; ++n) acc[m][n] = zero4;

    for (int it = 0; it < F_ / BK; ++it) {
        int k0 = it * BK;
        __syncthreads();
        gld_lds16(ag0 + k0, (char*)&As[0][0] + w * 1024);
        gld_lds16(ag1 + k0, (char*)&As[0][0] + 4096 + w * 1024);
        float4 b0 = *(const float4*)(wdp + k0);
        float4 b1 = *(const float4*)(wdp + k0 + 4);
        float4 b2 = *(const float4*)(wdp + k0 + 8);
        float4 b3 = *(const float4*)(wdp + k0 + 12);
        *(short8*)(&Bs[brow][bhalf * 16])     = pack8(b0, b1);
        *(short8*)(&Bs[brow][bhalf * 16 + 8]) = pack8(b2, b3);
        __syncthreads();

        int wr = w >> 1, wc = w & 1;
        short8 af[4];
        #pragma unroll
        for (int m = 0; m < 4; ++m)
            af[m] = *(const short8*)&As[wr * 64 + m * 16 + lr][kb8];
        #pragma unroll
        for (int n = 0; n < 4; ++n) {
            short8 bn = *(const short8*)&Bs[wc * 64 + n * 16 + lr][kb8];
            #pragma unroll
            for (int m = 0; m < 4; ++m)
                acc[m][n] = __builtin_amdgcn_mfma_f32_16x16x32_bf16(af[m], bn, acc[m][n], 0, 0, 0);
        }
    }

    int wr = w >> 1, wc = w & 1;
    #pragma unroll
    for (int m = 0; m < 4; ++m) {
        #pragma unroll
        for (int q = 0; q < 4; ++q) {
            int row = wr * 64 + m * 16 + (l >> 4) * 4 + q;
            if (row < rows) {
                int   tkn = tok[e * T_ + base + row];
                float wt  = gwslot[e * T_ + base + row];
                #pragma unroll
                for (int n = 0; n < 4; ++n) {
                    int col = hj * BN + wc * 64 + n * 16 + lr;
                    atomicAdd(&out[(size_t)tkn * H_ + col], wt * acc[m][n][q]);
                }
            }
        }
    }
}

// ---------------- launch ----------------
extern "C" void kernel_launch(void* const* d_in, const int* in_sizes, int n_in,
                              void* d_out, int out_size, void* d_ws, size_t ws_size,
                              hipStream_t stream)
{
    const float* x     = (const float*)d_in[0];
    const float* lnw   = (const float*)d_in[1];
    const float* lnb   = (const float*)d_in[2];
    const float* gatew = (const float*)d_in[3];
    const float* Wg    = (const float*)d_in[4];
    const float* Wu    = (const float*)d_in[5];
    const float* Wd    = (const float*)d_in[6];
    float* out = (float*)d_out;

    char* ws = (char*)d_ws;
    unsigned short* xn     = (unsigned short*)ws;                       // 4 MB
    int*            tokl   = (int*)  (ws + (4u << 20));                 // 64 KB
    float*          gwslot = (float*)(ws + (4u << 20) + (64u << 10));   // 64 KB
    int*            cnt    = (int*)  (ws + (4u << 20) + (128u << 10));  // 64 B
    int*            offs   = cnt + 16;
    unsigned short* hbuf   = (unsigned short*)(ws + (4u << 20) + (128u << 10) + 256); // 32 MB

    hipMemsetAsync(cnt, 0, 64, stream);
    ln_gate_kernel<<<T_, 256, 0, stream>>>(x, lnw, lnb, gatew, out, xn, tokl, gwslot, cnt);
    finalize_kernel<<<1, 64, 0, stream>>>(cnt, offs, out + (size_t)T_ * H_);
    gu_kernel<<<dim3(T_ / BM, F_ / BN, E_), 256, 0, stream>>>(Wg, Wu, xn, tokl, cnt, offs, hbuf);
    down_kernel<<<dim3(T_ / BM, H_ / BN, E_), 256, 0, stream>>>(Wd, hbuf, tokl, cnt, offs, gwslot, out);
}

// Round 7
// 781.239 us; speedup vs baseline: 2.1731x; 2.1731x over previous
//
#include <hip/hip_runtime.h>
#include <hip/hip_bf16.h>

// Problem constants (B=1, S=2048, H=1024, E=8, K=2, F=4096)
#define T_ 2048
#define H_ 1024
#define E_ 8
#define F_ 4096

#define BM 128
#define BN 128
#define BK 32

typedef __attribute__((ext_vector_type(8))) short short8;
typedef __attribute__((ext_vector_type(4))) float f32x4;

__device__ __forceinline__ unsigned short f2bf(float f) {
    union { float f; unsigned u; } a; a.f = f;
    unsigned r = a.u + 0x7fffu + ((a.u >> 16) & 1u);   // RNE (finite inputs)
    return (unsigned short)(r >> 16);
}

__device__ __forceinline__ short8 pack8(float4 a, float4 b) {
    short8 r;
    r[0] = (short)f2bf(a.x); r[1] = (short)f2bf(a.y);
    r[2] = (short)f2bf(a.z); r[3] = (short)f2bf(a.w);
    r[4] = (short)f2bf(b.x); r[5] = (short)f2bf(b.y);
    r[6] = (short)f2bf(b.z); r[7] = (short)f2bf(b.w);
    return r;
}

__device__ __forceinline__ void gld_lds16(const void* g, void* l) {
    __builtin_amdgcn_global_load_lds(
        (const __attribute__((address_space(1))) unsigned int*)g,
        (__attribute__((address_space(3))) unsigned int*)l,
        16, 0, 0);
}

// ---------------- Kernel 0: fp32 -> bf16 weight conversion (fast path) ----------------
__global__ __launch_bounds__(256) void convert_kernel(
    const float* __restrict__ src, unsigned short* __restrict__ dst, int n8)
{
    int i = blockIdx.x * blockDim.x + threadIdx.x;
    int stride = gridDim.x * blockDim.x;
    for (; i < n8; i += stride) {
        const float4* s = reinterpret_cast<const float4*>(src + (size_t)i * 8);
        float4 a = s[0], b = s[1];
        reinterpret_cast<short8*>(dst)[i] = pack8(a, b);
    }
}

// ---------------- Kernel 1: LayerNorm + residual copy + gating ----------------
__global__ __launch_bounds__(256) void ln_gate_kernel(
    const float* __restrict__ x, const float* __restrict__ lnw,
    const float* __restrict__ lnb, const float* __restrict__ gatew,
    float* __restrict__ out, unsigned short* __restrict__ xn,
    int* __restrict__ tok, float* __restrict__ gwslot, int* __restrict__ cnt)
{
    int t = blockIdx.x;
    int tid = threadIdx.x;
    const float4* xr = reinterpret_cast<const float4*>(x + (size_t)t * H_);
    float4 v = xr[tid];
    float s  = v.x + v.y + v.z + v.w;
    float ss = v.x*v.x + v.y*v.y + v.z*v.z + v.w*v.w;
    #pragma unroll
    for (int off = 32; off >= 1; off >>= 1) {
        s  += __shfl_xor(s, off);
        ss += __shfl_xor(ss, off);
    }
    __shared__ float redS[4], redQ[4];
    __shared__ float gred[4][E_];
    int wv = tid >> 6;
    if ((tid & 63) == 0) { redS[wv] = s; redQ[wv] = ss; }
    __syncthreads();
    s  = redS[0] + redS[1] + redS[2] + redS[3];
    ss = redQ[0] + redQ[1] + redQ[2] + redQ[3];
    float mu  = s * (1.0f / H_);
    float var = ss * (1.0f / H_) - mu * mu;
    float inv = rsqrtf(var + 1e-5f);

    float4 w4 = reinterpret_cast<const float4*>(lnw)[tid];
    float4 b4 = reinterpret_cast<const float4*>(lnb)[tid];
    float n0 = (v.x - mu) * inv * w4.x + b4.x;
    float n1 = (v.y - mu) * inv * w4.y + b4.y;
    float n2 = (v.z - mu) * inv * w4.z + b4.z;
    float n3 = (v.w - mu) * inv * w4.w + b4.w;

    ushort4 pk = make_ushort4(f2bf(n0), f2bf(n1), f2bf(n2), f2bf(n3));
    reinterpret_cast<ushort4*>(xn + (size_t)t * H_)[tid] = pk;
    reinterpret_cast<float4*>(out + (size_t)t * H_)[tid] = v;

    float lg[E_];
    #pragma unroll
    for (int e = 0; e < E_; ++e) {
        float4 g4 = reinterpret_cast<const float4*>(gatew + (size_t)e * H_)[tid];
        lg[e] = n0*g4.x + n1*g4.y + n2*g4.z + n3*g4.w;
    }
    #pragma unroll
    for (int e = 0; e < E_; ++e) {
        #pragma unroll
        for (int off = 32; off >= 1; off >>= 1)
            lg[e] += __shfl_xor(lg[e], off);
    }
    if ((tid & 63) == 0) {
        #pragma unroll
        for (int e = 0; e < E_; ++e) gred[wv][e] = lg[e];
    }
    __syncthreads();
    if (tid == 0) {
        float logit[E_]; float mx = -1e30f;
        #pragma unroll
        for (int e = 0; e < E_; ++e) {
            logit[e] = gred[0][e] + gred[1][e] + gred[2][e] + gred[3][e];
            mx = fmaxf(mx, logit[e]);
        }
        float p[E_]; float sum = 0.f;
        #pragma unroll
        for (int e = 0; e < E_; ++e) { p[e] = expf(logit[e] - mx); sum += p[e]; }
        int i0 = 0;
        #pragma unroll
        for (int e = 1; e < E_; ++e) if (logit[e] > logit[i0]) i0 = e;
        int i1 = (i0 == 0) ? 1 : 0;
        #pragma unroll
        for (int e = 0; e < E_; ++e) if (e != i0 && logit[e] > logit[i1]) i1 = e;
        float p0 = p[i0] / sum, p1 = p[i1] / sum;
        float dn = p0 + p1 + 1e-8f;
        float w0 = p0 / dn, w1 = p1 / dn;
        int pos0 = atomicAdd(&cnt[i0], 1);
        tok[i0 * T_ + pos0] = t; gwslot[i0 * T_ + pos0] = w0;
        int pos1 = atomicAdd(&cnt[i1], 1);
        tok[i1 * T_ + pos1] = t; gwslot[i1 * T_ + pos1] = w1;
    }
}

// ---------------- Kernel 2: lbl scalar + prefix offsets ----------------
__global__ void finalize_kernel(const int* __restrict__ cnt, int* __restrict__ offs,
                                float* __restrict__ lbl_out)
{
    if (threadIdx.x == 0 && blockIdx.x == 0) {
        int c[E_]; int tot = 0;
        #pragma unroll
        for (int e = 0; e < E_; ++e) { c[e] = cnt[e]; tot += c[e]; }
        int o = 0;
        #pragma unroll
        for (int e = 0; e < E_; ++e) { offs[e] = o; o += c[e]; }
        float itot = 1.0f / (float)tot;
        float u[E_]; float mean = 0.f;
        #pragma unroll
        for (int e = 0; e < E_; ++e) { u[e] = c[e] * itot; mean += u[e]; }
        mean *= (1.0f / E_);
        float var = 0.f;
        #pragma unroll
        for (int e = 0; e < E_; ++e) { float d = u[e] - mean; var += d * d; }
        var *= (1.0f / (E_ - 1));
        float l = var / (mean + 1e-8f);
        lbl_out[0] = l * l;
    }
}

// ======================= FAST PATH (bf16 weights in ws) =======================
// XOR chunk swizzle: LDS linear; global source chunk = (l&3)^((l>>3)&3);
// read slot = kc ^ ((row>>1)&3). 16 lanes -> 8 bank-groups = 2-way = free.

__global__ __launch_bounds__(256) void gu_fast(
    const unsigned short* __restrict__ Wgb, const unsigned short* __restrict__ Wub,
    const unsigned short* __restrict__ xn,
    const int* __restrict__ tok, const int* __restrict__ cnt,
    const int* __restrict__ offs, unsigned short* __restrict__ hbuf)
{
    int fj = blockIdx.x, ti = blockIdx.y, e = blockIdx.z;
    int Te = cnt[e];
    int base = ti * BM;
    if (base >= Te) return;
    int rows = Te - base; if (rows > BM) rows = BM;

    __shared__ unsigned short As[BM * BK];
    __shared__ unsigned short Bg[BN * BK];
    __shared__ unsigned short Bu[BN * BK];
    __shared__ int toks[BM];

    int tid = threadIdx.x;
    if (tid < BM) {
        int r = base + tid;
        toks[tid] = tok[e * T_ + (r < Te ? r : Te - 1)];
    }
    __syncthreads();

    int w = tid >> 6, l = tid & 63;
    int lr = l & 15, kc = l >> 4;
    int r0   = w * 16 + (l >> 2);
    int csrc = (l & 3) ^ ((l >> 3) & 3);

    const unsigned short* agA = xn + (size_t)toks[r0]      * H_ + csrc * 8;
    const unsigned short* agB = xn + (size_t)toks[r0 + 64] * H_ + csrc * 8;
    const unsigned short* bg0 = Wgb + ((size_t)e * F_ + (size_t)fj * BN + r0) * H_ + csrc * 8;
    const unsigned short* bg1 = bg0 + (size_t)64 * H_;
    const unsigned short* bu0 = Wub + ((size_t)e * F_ + (size_t)fj * BN + r0) * H_ + csrc * 8;
    const unsigned short* bu1 = bu0 + (size_t)64 * H_;

    char* AsB = (char*)As; char* BgB = (char*)Bg; char* BuB = (char*)Bu;

    f32x4 zero4 = {0.f, 0.f, 0.f, 0.f};
    f32x4 accg[4][4], accu[4][4];
    #pragma unroll
    for (int m = 0; m < 4; ++m)
        #pragma unroll
        for (int n = 0; n < 4; ++n) { accg[m][n] = zero4; accu[m][n] = zero4; }

    int wr = w >> 1, wc = w & 1;

    for (int it = 0; it < H_ / BK; ++it) {
        int k0 = it * BK;
        __syncthreads();
        gld_lds16(agA + k0, AsB + w * 1024);
        gld_lds16(agB + k0, AsB + 4096 + w * 1024);
        gld_lds16(bg0 + k0, BgB + w * 1024);
        gld_lds16(bg1 + k0, BgB + 4096 + w * 1024);
        gld_lds16(bu0 + k0, BuB + w * 1024);
        gld_lds16(bu1 + k0, BuB + 4096 + w * 1024);
        __syncthreads();

        short8 af[4];
        #pragma unroll
        for (int m = 0; m < 4; ++m) {
            int rowA = wr * 64 + m * 16 + lr;
            int sA = kc ^ ((rowA >> 1) & 3);
            af[m] = *(const short8*)(AsB + rowA * 64 + sA * 16);
        }
        #pragma unroll
        for (int n = 0; n < 4; ++n) {
            int rowB = wc * 64 + n * 16 + lr;
            int sB = kc ^ ((rowB >> 1) & 3);
            short8 bgn = *(const short8*)(BgB + rowB * 64 + sB * 16);
            #pragma unroll
            for (int m = 0; m < 4; ++m)
                accg[m][n] = __builtin_amdgcn_mfma_f32_16x16x32_bf16(af[m], bgn, accg[m][n], 0, 0, 0);
        }
        #pragma unroll
        for (int n = 0; n < 4; ++n) {
            int rowB = wc * 64 + n * 16 + lr;
            int sB = kc ^ ((rowB >> 1) & 3);
            short8 bun = *(const short8*)(BuB + rowB * 64 + sB * 16);
            #pragma unroll
            for (int m = 0; m < 4; ++m)
                accu[m][n] = __builtin_amdgcn_mfma_f32_16x16x32_bf16(af[m], bun, accu[m][n], 0, 0, 0);
        }
    }

    size_t slotbase = (size_t)offs[e] + base;
    #pragma unroll
    for (int m = 0; m < 4; ++m) {
        #pragma unroll
        for (int n = 0; n < 4; ++n) {
            int col = fj * BN + wc * 64 + n * 16 + lr;
            #pragma unroll
            for (int q = 0; q < 4; ++q) {
                int row = wr * 64 + m * 16 + (l >> 4) * 4 + q;
                if (row < rows) {
                    float uu = accu[m][n][q];
                    float hh = accg[m][n][q] * (uu / (1.f + expf(-uu)));
                    hbuf[(slotbase + row) * F_ + col] = f2bf(hh);
                }
            }
        }
    }
}

__global__ __launch_bounds__(256) void down_fast(
    const unsigned short* __restrict__ Wdb, const unsigned short* __restrict__ hbuf,
    const int* __restrict__ tok, const int* __restrict__ cnt,
    const int* __restrict__ offs, const float* __restrict__ gwslot,
    float* __restrict__ out)
{
    int hj = blockIdx.x, ti = blockIdx.y, e = blockIdx.z;
    int Te = cnt[e];
    int base = ti * BM;
    if (base >= Te) return;
    int rows = Te - base; if (rows > BM) rows = BM;

    __shared__ unsigned short As[BM * BK];
    __shared__ unsigned short Bs[BN * BK];

    int tid = threadIdx.x;
    int w = tid >> 6, l = tid & 63;
    int lr = l & 15, kc = l >> 4;
    int r0   = w * 16 + (l >> 2);
    int csrc = (l & 3) ^ ((l >> 3) & 3);

    size_t slot0 = (size_t)offs[e] + base;
    size_t arA = slot0 + r0;      if (arA > (size_t)(T_ * 2 - 1)) arA = T_ * 2 - 1;
    size_t arB = slot0 + r0 + 64; if (arB > (size_t)(T_ * 2 - 1)) arB = T_ * 2 - 1;
    const unsigned short* agA = hbuf + arA * F_ + csrc * 8;
    const unsigned short* agB = hbuf + arB * F_ + csrc * 8;
    const unsigned short* bd0 = Wdb + ((size_t)e * H_ + (size_t)hj * BN + r0) * F_ + csrc * 8;
    const unsigned short* bd1 = bd0 + (size_t)64 * F_;

    char* AsB = (char*)As; char* BsB = (char*)Bs;

    f32x4 zero4 = {0.f, 0.f, 0.f, 0.f};
    f32x4 acc[4][4];
    #pragma unroll
    for (int m = 0; m < 4; ++m)
        #pragma unroll
        for (int n = 0; n < 4; ++n) acc[m][n] = zero4;

    int wr = w >> 1, wc = w & 1;

    for (int it = 0; it < F_ / BK; ++it) {
        int k0 = it * BK;
        __syncthreads();
        gld_lds16(agA + k0, AsB + w * 1024);
        gld_lds16(agB + k0, AsB + 4096 + w * 1024);
        gld_lds16(bd0 + k0, BsB + w * 1024);
        gld_lds16(bd1 + k0, BsB + 4096 + w * 1024);
        __syncthreads();

        short8 af[4];
        #pragma unroll
        for (int m = 0; m < 4; ++m) {
            int rowA = wr * 64 + m * 16 + lr;
            int sA = kc ^ ((rowA >> 1) & 3);
            af[m] = *(const short8*)(AsB + rowA * 64 + sA * 16);
        }
        #pragma unroll
        for (int n = 0; n < 4; ++n) {
            int rowB = wc * 64 + n * 16 + lr;
            int sB = kc ^ ((rowB >> 1) & 3);
            short8 bn = *(const short8*)(BsB + rowB * 64 + sB * 16);
            #pragma unroll
            for (int m = 0; m < 4; ++m)
                acc[m][n] = __builtin_amdgcn_mfma_f32_16x16x32_bf16(af[m], bn, acc[m][n], 0, 0, 0);
        }
    }

    #pragma unroll
    for (int m = 0; m < 4; ++m) {
        #pragma unroll
        for (int q = 0; q < 4; ++q) {
            int row = wr * 64 + m * 16 + (l >> 4) * 4 + q;
            if (row < rows) {
                int   tkn = tok[e * T_ + base + row];
                float wt  = gwslot[e * T_ + base + row];
                #pragma unroll
                for (int n = 0; n < 4; ++n) {
                    int col = hj * BN + wc * 64 + n * 16 + lr;
                    atomicAdd(&out[(size_t)tkn * H_ + col], wt * acc[m][n][q]);
                }
            }
        }
    }
}

// ======================= FALLBACK PATH (fp32 weights, reg-pack) =======================
__global__ __launch_bounds__(256) void gu_kernel(
    const float* __restrict__ Wg, const float* __restrict__ Wu,
    const unsigned short* __restrict__ xn,
    const int* __restrict__ tok, const int* __restrict__ cnt,
    const int* __restrict__ offs, unsigned short* __restrict__ hbuf)
{
    int ti = blockIdx.x, fj = blockIdx.y, e = blockIdx.z;
    int Te = cnt[e];
    int base = ti * BM;
    if (base >= Te) return;
    int rows = Te - base; if (rows > BM) rows = BM;

    __shared__ unsigned short As[BM][BK];
    __shared__ unsigned short Bgs[BN][BK];
    __shared__ unsigned short Bus[BN][BK];
    __shared__ int toks[BM];

    int tid = threadIdx.x;
    if (tid < BM) {
        int r = base + tid;
        toks[tid] = tok[e * T_ + (r < Te ? r : Te - 1)];
    }
    __syncthreads();

    int w = tid >> 6, l = tid & 63;
    int lr = l & 15, kb8 = (l >> 4) * 8;
    int arow0 = tid >> 2, achk = tid & 3;
    const unsigned short* ag0 = xn + (size_t)toks[arow0]      * H_ + achk * 8;
    const unsigned short* ag1 = xn + (size_t)toks[arow0 + 64] * H_ + achk * 8;

    int brow = tid >> 1, bhalf = tid & 1;
    const float* wgp = Wg + ((size_t)e * F_ + (size_t)fj * BN + brow) * H_ + bhalf * 16;
    const float* wup = Wu + ((size_t)e * F_ + (size_t)fj * BN + brow) * H_ + bhalf * 16;

    f32x4 zero4 = {0.f, 0.f, 0.f, 0.f};
    f32x4 accg[4][4], accu[4][4];
    #pragma unroll
    for (int m = 0; m < 4; ++m)
        #pragma unroll
        for (int n = 0; n < 4; ++n) { accg[m][n] = zero4; accu[m][n] = zero4; }

    for (int it = 0; it < H_ / BK; ++it) {
        int k0 = it * BK;
        __syncthreads();
        gld_lds16(ag0 + k0, (char*)&As[0][0] + w * 1024);
        gld_lds16(ag1 + k0, (char*)&As[0][0] + 4096 + w * 1024);
        float4 g0 = *(const float4*)(wgp + k0);
        float4 g1 = *(const float4*)(wgp + k0 + 4);
        float4 g2 = *(const float4*)(wgp + k0 + 8);
        float4 g3 = *(const float4*)(wgp + k0 + 12);
        float4 u0 = *(const float4*)(wup + k0);
        float4 u1 = *(const float4*)(wup + k0 + 4);
        float4 u2 = *(const float4*)(wup + k0 + 8);
        float4 u3 = *(const float4*)(wup + k0 + 12);
        *(short8*)(&Bgs[brow][bhalf * 16])     = pack8(g0, g1);
        *(short8*)(&Bgs[brow][bhalf * 16 + 8]) = pack8(g2, g3);
        *(short8*)(&Bus[brow][bhalf * 16])     = pack8(u0, u1);
        *(short8*)(&Bus[brow][bhalf * 16 + 8]) = pack8(u2, u3);
        __syncthreads();

        int wr = w >> 1, wc = w & 1;
        short8 af[4];
        #pragma unroll
        for (int m = 0; m < 4; ++m)
            af[m] = *(const short8*)&As[wr * 64 + m * 16 + lr][kb8];
        #pragma unroll
        for (int n = 0; n < 4; ++n) {
            short8 bgn = *(const short8*)&Bgs[wc * 64 + n * 16 + lr][kb8];
            #pragma unroll
            for (int m = 0; m < 4; ++m)
                accg[m][n] = __builtin_amdgcn_mfma_f32_16x16x32_bf16(af[m], bgn, accg[m][n], 0, 0, 0);
        }
        #pragma unroll
        for (int n = 0; n < 4; ++n) {
            short8 bun = *(const short8*)&Bus[wc * 64 + n * 16 + lr][kb8];
            #pragma unroll
            for (int m = 0; m < 4; ++m)
                accu[m][n] = __builtin_amdgcn_mfma_f32_16x16x32_bf16(af[m], bun, accu[m][n], 0, 0, 0);
        }
    }

    int wr = w >> 1, wc = w & 1;
    size_t slotbase = (size_t)offs[e] + base;
    #pragma unroll
    for (int m = 0; m < 4; ++m) {
        #pragma unroll
        for (int n = 0; n < 4; ++n) {
            int col = fj * BN + wc * 64 + n * 16 + lr;
            #pragma unroll
            for (int q = 0; q < 4; ++q) {
                int row = wr * 64 + m * 16 + (l >> 4) * 4 + q;
                if (row < rows) {
                    float uu = accu[m][n][q];
                    float hh = accg[m][n][q] * (uu / (1.f + expf(-uu)));
                    hbuf[(slotbase + row) * F_ + col] = f2bf(hh);
                }
            }
        }
    }
}

__global__ __launch_bounds__(256) void down_kernel(
    const float* __restrict__ Wd, const unsigned short* __restrict__ hbuf,
    const int* __restrict__ tok, const int* __restrict__ cnt,
    const int* __restrict__ offs, const float* __restrict__ gwslot,
    float* __restrict__ out)
{
    int ti = blockIdx.x, hj = blockIdx.y, e = blockIdx.z;
    int Te = cnt[e];
    int base = ti * BM;
    if (base >= Te) return;
    int rows = Te - base; if (rows > BM) rows = BM;

    __shared__ unsigned short As[BM][BK];
    __shared__ unsigned short Bs[BN][BK];

    int tid = threadIdx.x;
    int w = tid >> 6, l = tid & 63;
    int lr = l & 15, kb8 = (l >> 4) * 8;
    int arow0 = tid >> 2, achk = tid & 3;
    size_t slot0 = (size_t)offs[e] + base;
    size_t ar0 = slot0 + arow0;      if (ar0 > (size_t)(T_ * 2 - 1)) ar0 = T_ * 2 - 1;
    size_t ar1 = slot0 + arow0 + 64; if (ar1 > (size_t)(T_ * 2 - 1)) ar1 = T_ * 2 - 1;
    const unsigned short* ag0 = hbuf + ar0 * F_ + achk * 8;
    const unsigned short* ag1 = hbuf + ar1 * F_ + achk * 8;

    int brow = tid >> 1, bhalf = tid & 1;
    const float* wdp = Wd + ((size_t)e * H_ + (size_t)hj * BN + brow) * F_ + bhalf * 16;

    f32x4 zero4 = {0.f, 0.f, 0.f, 0.f};
    f32x4 acc[4][4];
    #pragma unroll
    for (int m = 0; m < 4; ++m)
        #pragma unroll
        for (int n = 0; n < 4; ++n) acc[m][n] = zero4;

    for (int it = 0; it < F_ / BK; ++it) {
        int k0 = it * BK;
        __syncthreads();
        gld_lds16(ag0 + k0, (char*)&As[0][0] + w * 1024);
        gld_lds16(ag1 + k0, (char*)&As[0][0] + 4096 + w * 1024);
        float4 b0 = *(const float4*)(wdp + k0);
        float4 b1 = *(const float4*)(wdp + k0 + 4);
        float4 b2 = *(const float4*)(wdp + k0 + 8);
        float4 b3 = *(const float4*)(wdp + k0 + 12);
        *(short8*)(&Bs[brow][bhalf * 16])     = pack8(b0, b1);
        *(short8*)(&Bs[brow][bhalf * 16 + 8]) = pack8(b2, b3);
        __syncthreads();

        int wr = w >> 1, wc = w & 1;
        short8 af[4];
        #pragma unroll
        for (int m = 0; m < 4; ++m)
            af[m] = *(const short8*)&As[wr * 64 + m * 16 + lr][kb8];
        #pragma unroll
        for (int n = 0; n < 4; ++n) {
            short8 bn = *(const short8*)&Bs[wc * 64 + n * 16 + lr][kb8];
            #pragma unroll
            for (int m = 0; m < 4; ++m)
                acc[m][n] = __builtin_amdgcn_mfma_f32_16x16x32_bf16(af[m], bn, acc[m][n], 0, 0, 0);
        }
    }

    int wr = w >> 1, wc = w & 1;
    #pragma unroll
    for (int m = 0; m < 4; ++m) {
        #pragma unroll
        for (int q = 0; q < 4; ++q) {
            int row = wr * 64 + m * 16 + (l >> 4) * 4 + q;
            if (row < rows) {
                int   tkn = tok[e * T_ + base + row];
                float wt  = gwslot[e * T_ + base + row];
                #pragma unroll
                for (int n = 0; n < 4; ++n) {
                    int col = hj * BN + wc * 64 + n * 16 + lr;
                    atomicAdd(&out[(size_t)tkn * H_ + col], wt * acc[m][n][q]);
                }
            }
        }
    }
}

// ---------------- launch ----------------
extern "C" void kernel_launch(void* const* d_in, const int* in_sizes, int n_in,
                              void* d_out, int out_size, void* d_ws, size_t ws_size,
                              hipStream_t stream)
{
    const float* x     = (const float*)d_in[0];
    const float* lnw   = (const float*)d_in[1];
    const float* lnb   = (const float*)d_in[2];
    const float* gatew = (const float*)d_in[3];
    const float* Wg    = (const float*)d_in[4];
    const float* Wu    = (const float*)d_in[5];
    const float* Wd    = (const float*)d_in[6];
    float* out = (float*)d_out;

    char* ws = (char*)d_ws;
    unsigned short* xn     = (unsigned short*)ws;                       // 4 MB
    int*            tokl   = (int*)  (ws + (4u << 20));                 // 64 KB
    float*          gwslot = (float*)(ws + (4u << 20) + (64u << 10));   // 64 KB
    int*            cnt    = (int*)  (ws + (4u << 20) + (128u << 10));  // 256 B
    int*            offs   = cnt + 16;
    unsigned short* hbuf   = (unsigned short*)(ws + (4u << 20) + (128u << 10) + 256); // 32 MB

    size_t bfw_off = (4u << 20) + (128u << 10) + 256 + (size_t)T_ * 2 * F_ * 2;
    unsigned short* Wgb = (unsigned short*)(ws + bfw_off);
    unsigned short* Wub = Wgb + (size_t)E_ * F_ * H_;
    unsigned short* Wdb = Wub + (size_t)E_ * F_ * H_;
    size_t need_full = bfw_off + 3ull * E_ * F_ * H_ * 2;

    hipMemsetAsync(cnt, 0, 64, stream);
    ln_gate_kernel<<<T_, 256, 0, stream>>>(x, lnw, lnb, gatew, out, xn, tokl, gwslot, cnt);
    finalize_kernel<<<1, 64, 0, stream>>>(cnt, offs, out + (size_t)T_ * H_);

    if (ws_size >= need_full) {
        int n8 = E_ * F_ * H_ / 8;   // 4,194,304 groups per tensor
        convert_kernel<<<8192, 256, 0, stream>>>(Wg, Wgb, n8);
        convert_kernel<<<8192, 256, 0, stream>>>(Wu, Wub, n8);
        convert_kernel<<<8192, 256, 0, stream>>>(Wd, Wdb, n8);
        gu_fast  <<<dim3(F_ / BN, T_ / BM, E_), 256, 0, stream>>>(Wgb, Wub, xn, tokl, cnt, offs, hbuf);
        down_fast<<<dim3(H_ / BN, T_ / BM, E_), 256, 0, stream>>>(Wdb, hbuf, tokl, cnt, offs, gwslot, out);
    } else {
        gu_kernel  <<<dim3(T_ / BM, F_ / BN, E_), 256, 0, stream>>>(Wg, Wu, xn, tokl, cnt, offs, hbuf);
        down_kernel<<<dim3(T_ / BM, H_ / BN, E_), 256, 0, stream>>>(Wd, hbuf, tokl, cnt, offs, gwslot, out);
    }
}

// Round 8
// 692.796 us; speedup vs baseline: 2.4505x; 1.1277x over previous
//
#include <hip/hip_runtime.h>
#include <hip/hip_bf16.h>

// Problem constants (B=1, S=2048, H=1024, E=8, K=2, F=4096)
#define T_ 2048
#define H_ 1024
#define E_ 8
#define F_ 4096

#define BM 128
#define BN 128
#define BK 32

typedef __attribute__((ext_vector_type(8))) short short8;
typedef __attribute__((ext_vector_type(4))) float f32x4;

__device__ __forceinline__ unsigned short f2bf(float f) {
    union { float f; unsigned u; } a; a.f = f;
    unsigned r = a.u + 0x7fffu + ((a.u >> 16) & 1u);   // RNE (finite inputs)
    return (unsigned short)(r >> 16);
}

__device__ __forceinline__ short8 pack8(float4 a, float4 b) {
    short8 r;
    r[0] = (short)f2bf(a.x); r[1] = (short)f2bf(a.y);
    r[2] = (short)f2bf(a.z); r[3] = (short)f2bf(a.w);
    r[4] = (short)f2bf(b.x); r[5] = (short)f2bf(b.y);
    r[6] = (short)f2bf(b.z); r[7] = (short)f2bf(b.w);
    return r;
}

__device__ __forceinline__ void gld_lds16(const void* g, void* l) {
    __builtin_amdgcn_global_load_lds(
        (const __attribute__((address_space(1))) unsigned int*)g,
        (__attribute__((address_space(3))) unsigned int*)l,
        16, 0, 0);
}

// ---------------- Kernel 0: fp32 -> bf16 weight conversion (3 tensors, 1 dispatch) ----------------
__global__ __launch_bounds__(256) void convert3_kernel(
    const float* __restrict__ s0, const float* __restrict__ s1, const float* __restrict__ s2,
    unsigned short* __restrict__ d0, unsigned short* __restrict__ d1, unsigned short* __restrict__ d2,
    int n8)
{
    const float* src      = blockIdx.y == 0 ? s0 : blockIdx.y == 1 ? s1 : s2;
    unsigned short* dst   = blockIdx.y == 0 ? d0 : blockIdx.y == 1 ? d1 : d2;
    int i = blockIdx.x * blockDim.x + threadIdx.x;
    int stride = gridDim.x * blockDim.x;
    for (; i < n8; i += stride) {
        const float4* s = reinterpret_cast<const float4*>(src + (size_t)i * 8);
        float4 a = s[0], b = s[1];
        reinterpret_cast<short8*>(dst)[i] = pack8(a, b);
    }
}

// ---------------- Kernel 1: LayerNorm + residual copy + gating ----------------
__global__ __launch_bounds__(256) void ln_gate_kernel(
    const float* __restrict__ x, const float* __restrict__ lnw,
    const float* __restrict__ lnb, const float* __restrict__ gatew,
    float* __restrict__ out, unsigned short* __restrict__ xn,
    int* __restrict__ tok, float* __restrict__ gwslot, int* __restrict__ cnt)
{
    int t = blockIdx.x;
    int tid = threadIdx.x;
    const float4* xr = reinterpret_cast<const float4*>(x + (size_t)t * H_);
    float4 v = xr[tid];
    float s  = v.x + v.y + v.z + v.w;
    float ss = v.x*v.x + v.y*v.y + v.z*v.z + v.w*v.w;
    #pragma unroll
    for (int off = 32; off >= 1; off >>= 1) {
        s  += __shfl_xor(s, off);
        ss += __shfl_xor(ss, off);
    }
    __shared__ float redS[4], redQ[4];
    __shared__ float gred[4][E_];
    int wv = tid >> 6;
    if ((tid & 63) == 0) { redS[wv] = s; redQ[wv] = ss; }
    __syncthreads();
    s  = redS[0] + redS[1] + redS[2] + redS[3];
    ss = redQ[0] + redQ[1] + redQ[2] + redQ[3];
    float mu  = s * (1.0f / H_);
    float var = ss * (1.0f / H_) - mu * mu;
    float inv = rsqrtf(var + 1e-5f);

    float4 w4 = reinterpret_cast<const float4*>(lnw)[tid];
    float4 b4 = reinterpret_cast<const float4*>(lnb)[tid];
    float n0 = (v.x - mu) * inv * w4.x + b4.x;
    float n1 = (v.y - mu) * inv * w4.y + b4.y;
    float n2 = (v.z - mu) * inv * w4.z + b4.z;
    float n3 = (v.w - mu) * inv * w4.w + b4.w;

    ushort4 pk = make_ushort4(f2bf(n0), f2bf(n1), f2bf(n2), f2bf(n3));
    reinterpret_cast<ushort4*>(xn + (size_t)t * H_)[tid] = pk;
    reinterpret_cast<float4*>(out + (size_t)t * H_)[tid] = v;

    float lg[E_];
    #pragma unroll
    for (int e = 0; e < E_; ++e) {
        float4 g4 = reinterpret_cast<const float4*>(gatew + (size_t)e * H_)[tid];
        lg[e] = n0*g4.x + n1*g4.y + n2*g4.z + n3*g4.w;
    }
    #pragma unroll
    for (int e = 0; e < E_; ++e) {
        #pragma unroll
        for (int off = 32; off >= 1; off >>= 1)
            lg[e] += __shfl_xor(lg[e], off);
    }
    if ((tid & 63) == 0) {
        #pragma unroll
        for (int e = 0; e < E_; ++e) gred[wv][e] = lg[e];
    }
    __syncthreads();
    if (tid == 0) {
        float logit[E_]; float mx = -1e30f;
        #pragma unroll
        for (int e = 0; e < E_; ++e) {
            logit[e] = gred[0][e] + gred[1][e] + gred[2][e] + gred[3][e];
            mx = fmaxf(mx, logit[e]);
        }
        float p[E_]; float sum = 0.f;
        #pragma unroll
        for (int e = 0; e < E_; ++e) { p[e] = expf(logit[e] - mx); sum += p[e]; }
        int i0 = 0;
        #pragma unroll
        for (int e = 1; e < E_; ++e) if (logit[e] > logit[i0]) i0 = e;
        int i1 = (i0 == 0) ? 1 : 0;
        #pragma unroll
        for (int e = 0; e < E_; ++e) if (e != i0 && logit[e] > logit[i1]) i1 = e;
        float p0 = p[i0] / sum, p1 = p[i1] / sum;
        float dn = p0 + p1 + 1e-8f;
        float w0 = p0 / dn, w1 = p1 / dn;
        int pos0 = atomicAdd(&cnt[i0], 1);
        tok[i0 * T_ + pos0] = t; gwslot[i0 * T_ + pos0] = w0;
        int pos1 = atomicAdd(&cnt[i1], 1);
        tok[i1 * T_ + pos1] = t; gwslot[i1 * T_ + pos1] = w1;
    }
}

// ---------------- Kernel 2: lbl scalar + prefix offsets ----------------
__global__ void finalize_kernel(const int* __restrict__ cnt, int* __restrict__ offs,
                                float* __restrict__ lbl_out)
{
    if (threadIdx.x == 0 && blockIdx.x == 0) {
        int c[E_]; int tot = 0;
        #pragma unroll
        for (int e = 0; e < E_; ++e) { c[e] = cnt[e]; tot += c[e]; }
        int o = 0;
        #pragma unroll
        for (int e = 0; e < E_; ++e) { offs[e] = o; o += c[e]; }
        float itot = 1.0f / (float)tot;
        float u[E_]; float mean = 0.f;
        #pragma unroll
        for (int e = 0; e < E_; ++e) { u[e] = c[e] * itot; mean += u[e]; }
        mean *= (1.0f / E_);
        float var = 0.f;
        #pragma unroll
        for (int e = 0; e < E_; ++e) { float d = u[e] - mean; var += d * d; }
        var *= (1.0f / (E_ - 1));
        float l = var / (mean + 1e-8f);
        lbl_out[0] = l * l;
    }
}

// ======================= FAST PATH (bf16 weights, double-buffered) =======================
// XOR chunk swizzle: LDS linear; global source chunk = (l&3)^((l>>3)&3);
// read slot = kc ^ ((row>>1)&3). 16 lanes -> 8 bank-groups = 2-way = free.
// 2-phase: STAGE(next) issued BEFORE compute(cur); one barrier/K-step at the end
// (its implicit vmcnt(0) lands after compute, so HBM latency hides under MFMA).

__global__ __launch_bounds__(256) void gu_fast(
    const unsigned short* __restrict__ Wgb, const unsigned short* __restrict__ Wub,
    const unsigned short* __restrict__ xn,
    const int* __restrict__ tok, const int* __restrict__ cnt,
    const int* __restrict__ offs, unsigned short* __restrict__ hbuf)
{
    int fj = blockIdx.x, ti = blockIdx.y, e = blockIdx.z;
    int Te = cnt[e];
    int base = ti * BM;
    if (base >= Te) return;
    int rows = Te - base; if (rows > BM) rows = BM;

    __shared__ unsigned short As[2][BM * BK];
    __shared__ unsigned short Bg[2][BN * BK];
    __shared__ unsigned short Bu[2][BN * BK];
    __shared__ int toks[BM];

    int tid = threadIdx.x;
    if (tid < BM) {
        int r = base + tid;
        toks[tid] = tok[e * T_ + (r < Te ? r : Te - 1)];
    }
    __syncthreads();

    int w = tid >> 6, l = tid & 63;
    int lr = l & 15, kc = l >> 4;
    int r0   = w * 16 + (l >> 2);
    int csrc = (l & 3) ^ ((l >> 3) & 3);

    const unsigned short* agA = xn + (size_t)toks[r0]      * H_ + csrc * 8;
    const unsigned short* agB = xn + (size_t)toks[r0 + 64] * H_ + csrc * 8;
    const unsigned short* bg0 = Wgb + ((size_t)e * F_ + (size_t)fj * BN + r0) * H_ + csrc * 8;
    const unsigned short* bg1 = bg0 + (size_t)64 * H_;
    const unsigned short* bu0 = Wub + ((size_t)e * F_ + (size_t)fj * BN + r0) * H_ + csrc * 8;
    const unsigned short* bu1 = bu0 + (size_t)64 * H_;

    f32x4 zero4 = {0.f, 0.f, 0.f, 0.f};
    f32x4 accg[4][4], accu[4][4];
    #pragma unroll
    for (int m = 0; m < 4; ++m)
        #pragma unroll
        for (int n = 0; n < 4; ++n) { accg[m][n] = zero4; accu[m][n] = zero4; }

    int wr = w >> 1, wc = w & 1;

    // prologue: stage tile 0 into buf 0
    {
        char* A = (char*)As[0]; char* G = (char*)Bg[0]; char* U = (char*)Bu[0];
        gld_lds16(agA, A + w * 1024); gld_lds16(agB, A + 4096 + w * 1024);
        gld_lds16(bg0, G + w * 1024); gld_lds16(bg1, G + 4096 + w * 1024);
        gld_lds16(bu0, U + w * 1024); gld_lds16(bu1, U + 4096 + w * 1024);
    }
    __syncthreads();

    for (int it = 0; it < H_ / BK; ++it) {
        int cur = it & 1;
        if (it + 1 < H_ / BK) {
            int k1 = (it + 1) * BK;
            char* A = (char*)As[cur ^ 1]; char* G = (char*)Bg[cur ^ 1]; char* U = (char*)Bu[cur ^ 1];
            gld_lds16(agA + k1, A + w * 1024); gld_lds16(agB + k1, A + 4096 + w * 1024);
            gld_lds16(bg0 + k1, G + w * 1024); gld_lds16(bg1 + k1, G + 4096 + w * 1024);
            gld_lds16(bu0 + k1, U + w * 1024); gld_lds16(bu1 + k1, U + 4096 + w * 1024);
        }
        const char* AsB = (const char*)As[cur];
        const char* BgB = (const char*)Bg[cur];
        const char* BuB = (const char*)Bu[cur];

        short8 af[4];
        #pragma unroll
        for (int m = 0; m < 4; ++m) {
            int rowA = wr * 64 + m * 16 + lr;
            int sA = kc ^ ((rowA >> 1) & 3);
            af[m] = *(const short8*)(AsB + rowA * 64 + sA * 16);
        }
        #pragma unroll
        for (int n = 0; n < 4; ++n) {
            int rowB = wc * 64 + n * 16 + lr;
            int sB = kc ^ ((rowB >> 1) & 3);
            short8 bgn = *(const short8*)(BgB + rowB * 64 + sB * 16);
            #pragma unroll
            for (int m = 0; m < 4; ++m)
                accg[m][n] = __builtin_amdgcn_mfma_f32_16x16x32_bf16(af[m], bgn, accg[m][n], 0, 0, 0);
        }
        #pragma unroll
        for (int n = 0; n < 4; ++n) {
            int rowB = wc * 64 + n * 16 + lr;
            int sB = kc ^ ((rowB >> 1) & 3);
            short8 bun = *(const short8*)(BuB + rowB * 64 + sB * 16);
            #pragma unroll
            for (int m = 0; m < 4; ++m)
                accu[m][n] = __builtin_amdgcn_mfma_f32_16x16x32_bf16(af[m], bun, accu[m][n], 0, 0, 0);
        }
        __syncthreads();   // drains vmcnt(0): next tile ready; cur buffer released
    }

    size_t slotbase = (size_t)offs[e] + base;
    #pragma unroll
    for (int m = 0; m < 4; ++m) {
        #pragma unroll
        for (int n = 0; n < 4; ++n) {
            int col = fj * BN + wc * 64 + n * 16 + lr;
            #pragma unroll
            for (int q = 0; q < 4; ++q) {
                int row = wr * 64 + m * 16 + kc * 4 + q;
                if (row < rows) {
                    float uu = accu[m][n][q];
                    float hh = accg[m][n][q] * (uu / (1.f + expf(-uu)));
                    hbuf[(slotbase + row) * F_ + col] = f2bf(hh);
                }
            }
        }
    }
}

// Split-K=2: blockIdx.z = e*2 + ks; each chunk covers F/2; atomics merge chunks.
__global__ __launch_bounds__(256) void down_fast(
    const unsigned short* __restrict__ Wdb, const unsigned short* __restrict__ hbuf,
    const int* __restrict__ tok, const int* __restrict__ cnt,
    const int* __restrict__ offs, const float* __restrict__ gwslot,
    float* __restrict__ out)
{
    int hj = blockIdx.x, ti = blockIdx.y;
    int e  = blockIdx.z >> 1, ks = blockIdx.z & 1;
    int Te = cnt[e];
    int base = ti * BM;
    if (base >= Te) return;
    int rows = Te - base; if (rows > BM) rows = BM;

    __shared__ unsigned short As[2][BM * BK];
    __shared__ unsigned short Bs[2][BN * BK];

    int tid = threadIdx.x;
    int w = tid >> 6, l = tid & 63;
    int lr = l & 15, kc = l >> 4;
    int r0   = w * 16 + (l >> 2);
    int csrc = (l & 3) ^ ((l >> 3) & 3);
    const int KOFF = ks * (F_ / 2);
    const int NT = (F_ / 2) / BK;   // 64

    size_t slot0 = (size_t)offs[e] + base;
    size_t arA = slot0 + r0;      if (arA > (size_t)(T_ * 2 - 1)) arA = T_ * 2 - 1;
    size_t arB = slot0 + r0 + 64; if (arB > (size_t)(T_ * 2 - 1)) arB = T_ * 2 - 1;
    const unsigned short* agA = hbuf + arA * F_ + KOFF + csrc * 8;
    const unsigned short* agB = hbuf + arB * F_ + KOFF + csrc * 8;
    const unsigned short* bd0 = Wdb + ((size_t)e * H_ + (size_t)hj * BN + r0) * F_ + KOFF + csrc * 8;
    const unsigned short* bd1 = bd0 + (size_t)64 * F_;

    f32x4 zero4 = {0.f, 0.f, 0.f, 0.f};
    f32x4 acc[4][4];
    #pragma unroll
    for (int m = 0; m < 4; ++m)
        #pragma unroll
        for (int n = 0; n < 4; ++n) acc[m][n] = zero4;

    int wr = w >> 1, wc = w & 1;

    {
        char* A = (char*)As[0]; char* B = (char*)Bs[0];
        gld_lds16(agA, A + w * 1024); gld_lds16(agB, A + 4096 + w * 1024);
        gld_lds16(bd0, B + w * 1024); gld_lds16(bd1, B + 4096 + w * 1024);
    }
    __syncthreads();

    for (int it = 0; it < NT; ++it) {
        int cur = it & 1;
        if (it + 1 < NT) {
            int k1 = (it + 1) * BK;
            char* A = (char*)As[cur ^ 1]; char* B = (char*)Bs[cur ^ 1];
            gld_lds16(agA + k1, A + w * 1024); gld_lds16(agB + k1, A + 4096 + w * 1024);
            gld_lds16(bd0 + k1, B + w * 1024); gld_lds16(bd1 + k1, B + 4096 + w * 1024);
        }
        const char* AsB = (const char*)As[cur];
        const char* BsB = (const char*)Bs[cur];

        short8 af[4];
        #pragma unroll
        for (int m = 0; m < 4; ++m) {
            int rowA = wr * 64 + m * 16 + lr;
            int sA = kc ^ ((rowA >> 1) & 3);
            af[m] = *(const short8*)(AsB + rowA * 64 + sA * 16);
        }
        #pragma unroll
        for (int n = 0; n < 4; ++n) {
            int rowB = wc * 64 + n * 16 + lr;
            int sB = kc ^ ((rowB >> 1) & 3);
            short8 bn = *(const short8*)(BsB + rowB * 64 + sB * 16);
            #pragma unroll
            for (int m = 0; m < 4; ++m)
                acc[m][n] = __builtin_amdgcn_mfma_f32_16x16x32_bf16(af[m], bn, acc[m][n], 0, 0, 0);
        }
        __syncthreads();
    }

    #pragma unroll
    for (int m = 0; m < 4; ++m) {
        #pragma unroll
        for (int q = 0; q < 4; ++q) {
            int row = wr * 64 + m * 16 + kc * 4 + q;
            if (row < rows) {
                int   tkn = tok[e * T_ + base + row];
                float wt  = gwslot[e * T_ + base + row];
                #pragma unroll
                for (int n = 0; n < 4; ++n) {
                    int col = hj * BN + wc * 64 + n * 16 + lr;
                    atomicAdd(&out[(size_t)tkn * H_ + col], wt * acc[m][n][q]);
                }
            }
        }
    }
}

// ======================= FALLBACK PATH (fp32 weights, reg-pack) =======================
__global__ __launch_bounds__(256) void gu_kernel(
    const float* __restrict__ Wg, const float* __restrict__ Wu,
    const unsigned short* __restrict__ xn,
    const int* __restrict__ tok, const int* __restrict__ cnt,
    const int* __restrict__ offs, unsigned short* __restrict__ hbuf)
{
    int ti = blockIdx.x, fj = blockIdx.y, e = blockIdx.z;
    int Te = cnt[e];
    int base = ti * BM;
    if (base >= Te) return;
    int rows = Te - base; if (rows > BM) rows = BM;

    __shared__ unsigned short As[BM][BK];
    __shared__ unsigned short Bgs[BN][BK];
    __shared__ unsigned short Bus[BN][BK];
    __shared__ int toks[BM];

    int tid = threadIdx.x;
    if (tid < BM) {
        int r = base + tid;
        toks[tid] = tok[e * T_ + (r < Te ? r : Te - 1)];
    }
    __syncthreads();

    int w = tid >> 6, l = tid & 63;
    int lr = l & 15, kb8 = (l >> 4) * 8;
    int arow0 = tid >> 2, achk = tid & 3;
    const unsigned short* ag0 = xn + (size_t)toks[arow0]      * H_ + achk * 8;
    const unsigned short* ag1 = xn + (size_t)toks[arow0 + 64] * H_ + achk * 8;

    int brow = tid >> 1, bhalf = tid & 1;
    const float* wgp = Wg + ((size_t)e * F_ + (size_t)fj * BN + brow) * H_ + bhalf * 16;
    const float* wup = Wu + ((size_t)e * F_ + (size_t)fj * BN + brow) * H_ + bhalf * 16;

    f32x4 zero4 = {0.f, 0.f, 0.f, 0.f};
    f32x4 accg[4][4], accu[4][4];
    #pragma unroll
    for (int m = 0; m < 4; ++m)
        #pragma unroll
        for (int n = 0; n < 4; ++n) { accg[m][n] = zero4; accu[m][n] = zero4; }

    for (int it = 0; it < H_ / BK; ++it) {
        int k0 = it * BK;
        __syncthreads();
        gld_lds16(ag0 + k0, (char*)&As[0][0] + w * 1024);
        gld_lds16(ag1 + k0, (char*)&As[0][0] + 4096 + w * 1024);
        float4 g0 = *(const float4*)(wgp + k0);
        float4 g1 = *(const float4*)(wgp + k0 + 4);
        float4 g2 = *(const float4*)(wgp + k0 + 8);
        float4 g3 = *(const float4*)(wgp + k0 + 12);
        float4 u0 = *(const float4*)(wup + k0);
        float4 u1 = *(const float4*)(wup + k0 + 4);
        float4 u2 = *(const float4*)(wup + k0 + 8);
        float4 u3 = *(const float4*)(wup + k0 + 12);
        *(short8*)(&Bgs[brow][bhalf * 16])     = pack8(g0, g1);
        *(short8*)(&Bgs[brow][bhalf * 16 + 8]) = pack8(g2, g3);
        *(short8*)(&Bus[brow][bhalf * 16])     = pack8(u0, u1);
        *(short8*)(&Bus[brow][bhalf * 16 + 8]) = pack8(u2, u3);
        __syncthreads();

        int wr = w >> 1, wc = w & 1;
        short8 af[4];
        #pragma unroll
        for (int m = 0; m < 4; ++m)
            af[m] = *(const short8*)&As[wr * 64 + m * 16 + lr][kb8];
        #pragma unroll
        for (int n = 0; n < 4; ++n) {
            short8 bgn = *(const short8*)&Bgs[wc * 64 + n * 16 + lr][kb8];
            #pragma unroll
            for (int m = 0; m < 4; ++m)
                accg[m][n] = __builtin_amdgcn_mfma_f32_16x16x32_bf16(af[m], bgn, accg[m][n], 0, 0, 0);
        }
        #pragma unroll
        for (int n = 0; n < 4; ++n) {
            short8 bun = *(const short8*)&Bus[wc * 64 + n * 16 + lr][kb8];
            #pragma unroll
            for (int m = 0; m < 4; ++m)
                accu[m][n] = __builtin_amdgcn_mfma_f32_16x16x32_bf16(af[m], bun, accu[m][n], 0, 0, 0);
        }
    }

    int wr = w >> 1, wc = w & 1;
    size_t slotbase = (size_t)offs[e] + base;
    #pragma unroll
    for (int m = 0; m < 4; ++m) {
        #pragma unroll
        for (int n = 0; n < 4; ++n) {
            int col = fj * BN + wc * 64 + n * 16 + lr;
            #pragma unroll
            for (int q = 0; q < 4; ++q) {
                int row = wr * 64 + m * 16 + (l >> 4) * 4 + q;
                if (row < rows) {
                    float uu = accu[m][n][q];
                    float hh = accg[m][n][q] * (uu / (1.f + expf(-uu)));
                    hbuf[(slotbase + row) * F_ + col] = f2bf(hh);
                }
            }
        }
    }
}

__global__ __launch_bounds__(256) void down_kernel(
    const float* __restrict__ Wd, const unsigned short* __restrict__ hbuf,
    const int* __restrict__ tok, const int* __restrict__ cnt,
    const int* __restrict__ offs, const float* __restrict__ gwslot,
    float* __restrict__ out)
{
    int ti = blockIdx.x, hj = blockIdx.y, e = blockIdx.z;
    int Te = cnt[e];
    int base = ti * BM;
    if (base >= Te) return;
    int rows = Te - base; if (rows > BM) rows = BM;

    __shared__ unsigned short As[BM][BK];
    __shared__ unsigned short Bs[BN][BK];

    int tid = threadIdx.x;
    int w = tid >> 6, l = tid & 63;
    int lr = l & 15, kb8 = (l >> 4) * 8;
    int arow0 = tid >> 2, achk = tid & 3;
    size_t slot0 = (size_t)offs[e] + base;
    size_t ar0 = slot0 + arow0;      if (ar0 > (size_t)(T_ * 2 - 1)) ar0 = T_ * 2 - 1;
    size_t ar1 = slot0 + arow0 + 64; if (ar1 > (size_t)(T_ * 2 - 1)) ar1 = T_ * 2 - 1;
    const unsigned short* ag0 = hbuf + ar0 * F_ + achk * 8;
    const unsigned short* ag1 = hbuf + ar1 * F_ + achk * 8;

    int brow = tid >> 1, bhalf = tid & 1;
    const float* wdp = Wd + ((size_t)e * H_ + (size_t)hj * BN + brow) * F_ + bhalf * 16;

    f32x4 zero4 = {0.f, 0.f, 0.f, 0.f};
    f32x4 acc[4][4];
    #pragma unroll
    for (int m = 0; m < 4; ++m)
        #pragma unroll
        for (int n = 0; n < 4; ++n) acc[m][n] = zero4;

    for (int it = 0; it < F_ / BK; ++it) {
        int k0 = it * BK;
        __syncthreads();
        gld_lds16(ag0 + k0, (char*)&As[0][0] + w * 1024);
        gld_lds16(ag1 + k0, (char*)&As[0][0] + 4096 + w * 1024);
        float4 b0 = *(const float4*)(wdp + k0);
        float4 b1 = *(const float4*)(wdp + k0 + 4);
        float4 b2 = *(const float4*)(wdp + k0 + 8);
        float4 b3 = *(const float4*)(wdp + k0 + 12);
        *(short8*)(&Bs[brow][bhalf * 16])     = pack8(b0, b1);
        *(short8*)(&Bs[brow][bhalf * 16 + 8]) = pack8(b2, b3);
        __syncthreads();

        int wr = w >> 1, wc = w & 1;
        short8 af[4];
        #pragma unroll
        for (int m = 0; m < 4; ++m)
            af[m] = *(const short8*)&As[wr * 64 + m * 16 + lr][kb8];
        #pragma unroll
        for (int n = 0; n < 4; ++n) {
            short8 bn = *(const short8*)&Bs[wc * 64 + n * 16 + lr][kb8];
            #pragma unroll
            for (int m = 0; m < 4; ++m)
                acc[m][n] = __builtin_amdgcn_mfma_f32_16x16x32_bf16(af[m], bn, acc[m][n], 0, 0, 0);
        }
    }

    int wr = w >> 1, wc = w & 1;
    #pragma unroll
    for (int m = 0; m < 4; ++m) {
        #pragma unroll
        for (int q = 0; q < 4; ++q) {
            int row = wr * 64 + m * 16 + (l >> 4) * 4 + q;
            if (row < rows) {
                int   tkn = tok[e * T_ + base + row];
                float wt  = gwslot[e * T_ + base + row];
                #pragma unroll
                for (int n = 0; n < 4; ++n) {
                    int col = hj * BN + wc * 64 + n * 16 + lr;
                    atomicAdd(&out[(size_t)tkn * H_ + col], wt * acc[m][n][q]);
                }
            }
        }
    }
}

// ---------------- launch ----------------
extern "C" void kernel_launch(void* const* d_in, const int* in_sizes, int n_in,
                              void* d_out, int out_size, void* d_ws, size_t ws_size,
                              hipStream_t stream)
{
    const float* x     = (const float*)d_in[0];
    const float* lnw   = (const float*)d_in[1];
    const float* lnb   = (const float*)d_in[2];
    const float* gatew = (const float*)d_in[3];
    const float* Wg    = (const float*)d_in[4];
    const float* Wu    = (const float*)d_in[5];
    const float* Wd    = (const float*)d_in[6];
    float* out = (float*)d_out;

    char* ws = (char*)d_ws;
    unsigned short* xn     = (unsigned short*)ws;                       // 4 MB
    int*            tokl   = (int*)  (ws + (4u << 20));                 // 64 KB
    float*          gwslot = (float*)(ws + (4u << 20) + (64u << 10));   // 64 KB
    int*            cnt    = (int*)  (ws + (4u << 20) + (128u << 10));  // 256 B
    int*            offs   = cnt + 16;
    unsigned short* hbuf   = (unsigned short*)(ws + (4u << 20) + (128u << 10) + 256); // 32 MB

    size_t bfw_off = (4u << 20) + (128u << 10) + 256 + (size_t)T_ * 2 * F_ * 2;
    unsigned short* Wgb = (unsigned short*)(ws + bfw_off);
    unsigned short* Wub = Wgb + (size_t)E_ * F_ * H_;
    unsigned short* Wdb = Wub + (size_t)E_ * F_ * H_;
    size_t need_full = bfw_off + 3ull * E_ * F_ * H_ * 2;

    hipMemsetAsync(cnt, 0, 64, stream);
    ln_gate_kernel<<<T_, 256, 0, stream>>>(x, lnw, lnb, gatew, out, xn, tokl, gwslot, cnt);
    finalize_kernel<<<1, 64, 0, stream>>>(cnt, offs, out + (size_t)T_ * H_);

    if (ws_size >= need_full) {
        int n8 = E_ * F_ * H_ / 8;   // 4,194,304 groups per tensor
        convert3_kernel<<<dim3(2048, 3), 256, 0, stream>>>(Wg, Wu, Wd, Wgb, Wub, Wdb, n8);
        gu_fast  <<<dim3(F_ / BN, T_ / BM, E_),     256, 0, stream>>>(Wgb, Wub, xn, tokl, cnt, offs, hbuf);
        down_fast<<<dim3(H_ / BN, T_ / BM, E_ * 2), 256, 0, stream>>>(Wdb, hbuf, tokl, cnt, offs, gwslot, out);
    } else {
        gu_kernel  <<<dim3(T_ / BM, F_ / BN, E_), 256, 0, stream>>>(Wg, Wu, xn, tokl, cnt, offs, hbuf);
        down_kernel<<<dim3(T_ / BM, H_ / BN, E_), 256, 0, stream>>>(Wd, hbuf, tokl, cnt, offs, gwslot, out);
    }
}